// Round 6
// baseline (124.985 us; speedup 1.0000x reference)
//
#include <hip/hip_runtime.h>
#include <math.h>

// Keep mul/add rounding deterministic in the discrete-sensitive chains
// (radius -> quantile -> grid). Score math uses explicit fmaf.
#pragma clang fp contract(off)

#define G_N 2048
#define P_N 16384
#define K_TOP 8
#define NBUCK 32768          // spatial-hash buckets (power of 2)
#define BCAP 128             // ids per bucket; overflow -> exact full scan

// SWAR guard bits: fields at bits 0/21/42, guard = bit 20 of each field.
#define GUARD64 ((1ull << 20) | (1ull << 41) | (1ull << 62))

// u32-offset layout in ws:
#define OFF_CNT 16                       // bucket counts [NBUCK]
#define OFF_OVC (OFF_CNT + NBUCK)        // oversized count [1]
#define OFF_OVL (OFF_OVC + 1)            // oversized ids [G_N]
#define OFF_ENT (OFF_OVL + G_N)          // bucket entries [NBUCK*BCAP]
#define OFF_BOX (OFF_ENT + NBUCK * BCAP) // SWAR boxes uint4 [G_N]

__device__ __forceinline__ void quat_R(const float* quat, int g, float R[3][3]) {
    float q0 = quat[g * 4 + 0], q1 = quat[g * 4 + 1], q2 = quat[g * 4 + 2], q3 = quat[g * 4 + 3];
    float nrm = sqrtf(q0 * q0 + q1 * q1 + q2 * q2 + q3 * q3);
    float w = q0 / nrm, x = q1 / nrm, y = q2 / nrm, z = q3 / nrm;
    R[0][0] = 1.0f - 2.0f * (y * y + z * z);
    R[0][1] = 2.0f * (x * y - w * z);
    R[0][2] = 2.0f * (x * z + w * y);
    R[1][0] = 2.0f * (x * y + w * z);
    R[1][1] = 1.0f - 2.0f * (x * x + z * z);
    R[1][2] = 2.0f * (y * z - w * x);
    R[2][0] = 2.0f * (x * z - w * y);
    R[2][1] = 2.0f * (y * z + w * x);
    R[2][2] = 1.0f - 2.0f * (x * x + y * y);
}

__device__ __forceinline__ float radius_axis(const float R[3][3], float s2x, float s2y, float s2z, int a) {
    float dc = (R[a][0] * R[a][0]) * s2x + (R[a][1] * R[a][1]) * s2y + (R[a][2] * R[a][2]) * s2z;
    return sqrtf(7.8147279f) * sqrtf(dc);
}

__device__ __forceinline__ void grid_params(const float* ws, float gmn[3], float& vox) {
#pragma unroll
    for (int t = 0; t < 3; ++t) {
        float lo = ws[t], hi = ws[3 + t];
        float size = hi - lo;
        gmn[t] = lo - 0.1f * size;
    }
    vox = ws[6] * 3.0f;
}

// full score for gaussian g at point (px,py,pz) — exact R4/R5 expression chain
__device__ __forceinline__ float score_g(const float* __restrict__ pos, const float* __restrict__ scl,
                                         const float* __restrict__ quat, int g,
                                         float px, float py, float pz,
                                         float pp0, float pp1, float pp2,
                                         float pp4, float pp5, float pp8) {
    float R[3][3];
    quat_R(quat, g, R);
    float sx = scl[g * 3 + 0], sy = scl[g * 3 + 1], sz = scl[g * 3 + 2];
    float inv2x = 1.0f / (sx * sx), inv2y = 1.0f / (sy * sy), inv2z = 1.0f / (sz * sz);
    float C[3][3];
#pragma unroll
    for (int i = 0; i < 3; ++i) {
        float t0 = R[i][0] * inv2x, t1 = R[i][1] * inv2y, t2 = R[i][2] * inv2z;
#pragma unroll
        for (int k = 0; k < 3; ++k)
            C[i][k] = t0 * R[k][0] + t1 * R[k][1] + t2 * R[k][2];
    }
    float gx = pos[g * 3 + 0], gy = pos[g * 3 + 1], gz = pos[g * 3 + 2];
    float b0 = C[0][0] * gx + C[0][1] * gy + C[0][2] * gz;
    float b1 = C[1][0] * gx + C[1][1] * gy + C[1][2] * gz;
    float b2 = C[2][0] * gx + C[2][1] * gy + C[2][2] * gz;
    float c0 = b0 * gx + b1 * gy + b2 * gz;
    float log_norm = -2.7568155996140179f - (logf(sx) + logf(sy) + logf(sz));
    float s1 = pp0 * C[0][0];
    s1 = fmaf(pp1, C[0][1], s1);
    s1 = fmaf(pp2, C[0][2], s1);
    s1 = fmaf(pp1, C[1][0], s1);
    s1 = fmaf(pp4, C[1][1], s1);
    s1 = fmaf(pp5, C[1][2], s1);
    s1 = fmaf(pp2, C[2][0], s1);
    s1 = fmaf(pp5, C[2][1], s1);
    s1 = fmaf(pp8, C[2][2], s1);
    float d = px * b0;
    d = fmaf(py, b1, d);
    d = fmaf(pz, b2, d);
    float quad = fmaf(-2.0f, d, s1) + c0;
    return fmaf(-0.5f, quad, log_norm);
}

// float -> order-preserving u32 (ascending), and inverse
__device__ __forceinline__ unsigned f2ord(float f) {
    unsigned u = __float_as_uint(f);
    return (u & 0x80000000u) ? ~u : (u | 0x80000000u);
}
__device__ __forceinline__ float ord2f(unsigned u) {
    unsigned v = (u & 0x80000000u) ? (u ^ 0x80000000u) : ~u;
    return __uint_as_float(v);
}

// Stats via exact radix-select: blocks 0-6 find the two order statistics for
// their quantile (ranks r, r+1 ascending) and write the interpolated value.
// Block 7 zeros the hash-table counters (ws is re-poisoned every launch).
__global__ __launch_bounds__(1024) void k_stats(const float* __restrict__ pos,
                                                const float* __restrict__ scl,
                                                const float* __restrict__ quat,
                                                float* __restrict__ ws) {
    int which = blockIdx.x;
    int tid = threadIdx.x;
    if (which == 7) {
        unsigned* u = (unsigned*)ws;
        for (int i = tid; i < NBUCK; i += 1024) u[OFF_CNT + i] = 0u;
        if (tid == 0) u[OFF_OVC] = 0u;
        return;
    }
    int a = (which < 3) ? which : (which < 6 ? which - 3 : 0);
    unsigned keys[2];
#pragma unroll
    for (int i = 0; i < 2; ++i) {
        int g = tid + i * 1024;
        float R[3][3];
        quat_R(quat, g, R);
        float sx = scl[g * 3 + 0], sy = scl[g * 3 + 1], sz = scl[g * 3 + 2];
        float rad = radius_axis(R, sx * sx, sy * sy, sz * sz, a);
        float v;
        if (which < 3)      v = pos[g * 3 + a] - rad;
        else if (which < 6) v = pos[g * 3 + a] + rad;
        else                v = rad;
        keys[i] = f2ord(v);
    }

    __shared__ unsigned hist[256];
    __shared__ unsigned sel[2];   // {digit, new rank}
    __shared__ unsigned res2[2];  // {count <= v_lo, min key > v_lo}

    int rank0 = (which < 3) ? 20 : ((which < 6) ? 2026 : 1023);
    unsigned prefix = 0, pmask = 0, rank = (unsigned)rank0;
#pragma unroll
    for (int pass = 0; pass < 4; ++pass) {
        int shift = 24 - 8 * pass;
        if (tid < 256) hist[tid] = 0u;
        __syncthreads();
#pragma unroll
        for (int i = 0; i < 2; ++i) {
            unsigned k = keys[i];
            if ((k & pmask) == prefix) atomicAdd(&hist[(k >> shift) & 255u], 1u);
        }
        __syncthreads();
        if (tid == 0) {
            unsigned cum = 0;
            unsigned d = 0;
            for (; d < 256; ++d) {
                unsigned c = hist[d];
                if (cum + c > rank) break;
                cum += c;
            }
            sel[0] = d;
            sel[1] = rank - cum;
        }
        __syncthreads();
        prefix |= sel[0] << shift;
        pmask |= 0xFFu << shift;
        rank = sel[1];
        __syncthreads();
    }
    // prefix == ordered key at rank0 (exact)
    if (tid < 2) res2[tid] = (tid == 0) ? 0u : 0xFFFFFFFFu;
    __syncthreads();
#pragma unroll
    for (int i = 0; i < 2; ++i) {
        unsigned k = keys[i];
        if (k <= prefix) atomicAdd(&res2[0], 1u);
        else atomicMin(&res2[1], k);
    }
    __syncthreads();
    if (tid == 0) {
        unsigned vlo = prefix;
        unsigned vhi = (res2[0] >= (unsigned)(rank0 + 2)) ? prefix : res2[1];
        float flo = ord2f(vlo), fhi = ord2f(vhi);
        float qq;
        if (which < 3) qq = 0.01f * 2047.0f;
        else if (which < 6) qq = 0.99f * 2047.0f;
        else qq = 0.5f * 2047.0f;
        int lo = (int)floorf(qq);
        float fr = qq - (float)lo;
        ws[which] = flo * (1.0f - fr) + fhi * fr;
    }
}

// Build: per-gaussian SWAR box + spatial-hash rasterization.
__global__ __launch_bounds__(256) void k_build(const float* __restrict__ pos,
                                               const float* __restrict__ scl,
                                               const float* __restrict__ quat,
                                               float* __restrict__ ws) {
    int g = blockIdx.x * blockDim.x + threadIdx.x;
    if (g >= G_N) return;
    float gmn[3], vox;
    grid_params(ws, gmn, vox);

    float R[3][3];
    quat_R(quat, g, R);
    float sx = scl[g * 3 + 0], sy = scl[g * 3 + 1], sz = scl[g * 3 + 2];
    float s2x = sx * sx, s2y = sy * sy, s2z = sz * sz;
    int gmini[3], gmaxi[3];
    long long nv = 1;
#pragma unroll
    for (int t = 0; t < 3; ++t) {
        float rad = radius_axis(R, s2x, s2y, s2z, t);
        float p = pos[g * 3 + t];
        int lo = (int)floorf(((p - rad) - gmn[t]) / vox);
        int hi = (int)floorf(((p + rad) - gmn[t]) / vox);
        lo = lo < 0 ? 0 : (lo > 1023 ? 1023 : lo);
        hi = hi < 0 ? 0 : (hi > 1023 ? 1023 : hi);
        gmini[t] = lo; gmaxi[t] = hi;
        nv *= (long long)(hi - lo + 1);
    }
    unsigned* u = (unsigned*)ws;
    bool oversized = nv > 64;
    if (oversized) {
        unsigned slot = atomicAdd(&u[OFF_OVC], 1u);
        u[OFF_OVL + slot] = (unsigned)g;
        gmini[0] = gmini[1] = gmini[2] = 0;
        gmaxi[0] = gmaxi[1] = gmaxi[2] = 2047;
    } else {
        for (int z = gmini[2]; z <= gmaxi[2]; ++z)
            for (int y = gmini[1]; y <= gmaxi[1]; ++y)
                for (int x = gmini[0]; x <= gmaxi[0]; ++x) {
                    unsigned h = ((unsigned)x * 73856093u ^ (unsigned)y * 19349663u
                                ^ (unsigned)z * 83492791u) & (NBUCK - 1);
                    unsigned old = atomicAdd(&u[OFF_CNT + h], 1u);
                    if (old < BCAP) u[OFF_ENT + h * BCAP + old] = (unsigned)g;
                }
    }
    unsigned long long A = (unsigned long long)gmini[0]
                         | ((unsigned long long)gmini[1] << 21)
                         | ((unsigned long long)gmini[2] << 42);
    unsigned long long B = ((unsigned long long)gmaxi[0]
                         | ((unsigned long long)gmaxi[1] << 21)
                         | ((unsigned long long)gmaxi[2] << 42)) | GUARD64;
    uint4* bx = (uint4*)(u + OFF_BOX);
    bx[g] = make_uint4((unsigned)(A & 0xffffffffu), (unsigned)(A >> 32),
                       (unsigned)(B & 0xffffffffu), (unsigned)(B >> 32));
}

// dedupe + strict-total-order (score desc, id asc) top-8 insert
__device__ __forceinline__ void ins8(float tv[K_TOP], int ti[K_TOP], float sc, int id) {
    bool dup = false;
#pragma unroll
    for (int j = 0; j < K_TOP; ++j) dup |= (ti[j] == id);
    if (dup) return;
    bool better = (sc > tv[K_TOP - 1]) || (sc == tv[K_TOP - 1] && id < ti[K_TOP - 1]);
    if (!better) return;
    tv[K_TOP - 1] = sc;
    ti[K_TOP - 1] = id;
#pragma unroll
    for (int j = K_TOP - 1; j > 0; --j) {
        bool sw = (tv[j] > tv[j - 1]) || (tv[j] == tv[j - 1] && ti[j] < ti[j - 1]);
        if (sw) {
            float fv = tv[j]; tv[j] = tv[j - 1]; tv[j - 1] = fv;
            int iv = ti[j]; ti[j] = ti[j - 1]; ti[j - 1] = iv;
        }
    }
}

// Match: one thread per point — bucket lookup + exact box verify + rare score.
__global__ __launch_bounds__(64) void k_match(const float* __restrict__ pos,
                                              const float* __restrict__ scl,
                                              const float* __restrict__ quat,
                                              const float* __restrict__ pts,
                                              const float* __restrict__ ws,
                                              float* __restrict__ out) {
    int p = blockIdx.x * 64 + threadIdx.x;
    float gmn[3], vox;
    grid_params(ws, gmn, vox);
    float px = pts[p * 3 + 0], py = pts[p * 3 + 1], pz = pts[p * 3 + 2];
    float fpx = floorf((px - gmn[0]) / vox);
    float fpy = floorf((py - gmn[1]) / vox);
    float fpz = floorf((pz - gmn[2]) / vox);
    bool valid = (fpx >= 0.0f) & (fpx <= 1023.0f) & (fpy >= 0.0f) & (fpy <= 1023.0f)
               & (fpz >= 0.0f) & (fpz <= 1023.0f);

    float pp0 = px * px, pp1 = px * py, pp2 = px * pz;
    float pp4 = py * py, pp5 = py * pz, pp8 = pz * pz;

    float tv[K_TOP];
    int ti[K_TOP];
#pragma unroll
    for (int j = 0; j < K_TOP; ++j) { tv[j] = -INFINITY; ti[j] = 0x7fffffff; }

    const unsigned* u = (const unsigned*)ws;
    const uint4* bx = (const uint4*)(u + OFF_BOX);

    if (valid) {
        int vx = (int)fpx, vy = (int)fpy, vz = (int)fpz;
        unsigned long long PV = (unsigned long long)(unsigned)vx
                              | ((unsigned long long)(unsigned)vy << 21)
                              | ((unsigned long long)(unsigned)vz << 42);
        unsigned long long PVG = PV | GUARD64;
        unsigned h = ((unsigned)vx * 73856093u ^ (unsigned)vy * 19349663u
                    ^ (unsigned)vz * 83492791u) & (NBUCK - 1);
        unsigned cnt = u[OFF_CNT + h];
        if (cnt <= BCAP) {
            for (unsigned i = 0; i < cnt; ++i) {
                int g = (int)u[OFF_ENT + h * BCAP + i];
                uint4 b4 = bx[g];
                unsigned long long A = (unsigned long long)b4.x | ((unsigned long long)b4.y << 32);
                unsigned long long B = (unsigned long long)b4.z | ((unsigned long long)b4.w << 32);
                if ((((PVG - A) & (B - PV)) & GUARD64) == GUARD64) {
                    float sc = score_g(pos, scl, quat, g, px, py, pz, pp0, pp1, pp2, pp4, pp5, pp8);
                    ins8(tv, ti, sc, g);
                }
            }
        } else {
            // bucket overflow: exact full scan (covers every gaussian incl. oversized)
            for (int g = 0; g < G_N; ++g) {
                uint4 b4 = bx[g];
                unsigned long long A = (unsigned long long)b4.x | ((unsigned long long)b4.y << 32);
                unsigned long long B = (unsigned long long)b4.z | ((unsigned long long)b4.w << 32);
                if ((((PVG - A) & (B - PV)) & GUARD64) == GUARD64) {
                    float sc = score_g(pos, scl, quat, g, px, py, pz, pp0, pp1, pp2, pp4, pp5, pp8);
                    ins8(tv, ti, sc, g);
                }
            }
        }
    }
    // oversized gaussians pass for every point (dedupe handles overlap with full scan)
    unsigned ovc = u[OFF_OVC];
    for (unsigned i = 0; i < ovc; ++i) {
        int g = (int)u[OFF_OVL + i];
        float sc = score_g(pos, scl, quat, g, px, py, pz, pp0, pp1, pp2, pp4, pp5, pp8);
        ins8(tv, ti, sc, g);
    }

#pragma unroll
    for (int j = 0; j < K_TOP; ++j) {
        bool fin = tv[j] > -INFINITY;
        out[p * K_TOP + j] = fin ? (float)ti[j] : -1.0f;
        out[P_N * K_TOP + p * K_TOP + j] = fin ? expf(tv[j]) : 0.0f;
    }
}

extern "C" void kernel_launch(void* const* d_in, const int* in_sizes, int n_in,
                              void* d_out, int out_size, void* d_ws, size_t ws_size,
                              hipStream_t stream) {
    const float* pos = (const float*)d_in[0];
    const float* scl = (const float*)d_in[1];
    const float* quat = (const float*)d_in[2];
    const float* pts = (const float*)d_in[3];
    float* ws = (float*)d_ws;
    float* out = (float*)d_out;

    k_stats<<<dim3(8), dim3(1024), 0, stream>>>(pos, scl, quat, ws);
    k_build<<<dim3(G_N / 256), dim3(256), 0, stream>>>(pos, scl, quat, ws);
    k_match<<<dim3(P_N / 64), dim3(64), 0, stream>>>(pos, scl, quat, pts, ws, out);
}

// Round 7
// 86.073 us; speedup vs baseline: 1.4521x; 1.4521x over previous
//
#include <hip/hip_runtime.h>
#include <math.h>

// Keep mul/add rounding deterministic in the discrete-sensitive chains
// (radius -> quantile -> grid). Score math uses explicit fmaf.
#pragma clang fp contract(off)

#define G_N 2048
#define P_N 16384
#define K_TOP 8
#define NBUCK 32768          // spatial-hash buckets (power of 2)
#define BCAP 128             // ids per bucket; overflow -> exact full scan

// SWAR guard bits: fields at bits 0/21/42, guard = bit 20 of each field.
#define GUARD64 ((1ull << 20) | (1ull << 41) | (1ull << 62))

// u32-offset layout in ws:
#define OFF_CNT 16                       // bucket counts [NBUCK]
#define OFF_OVC (OFF_CNT + NBUCK)        // oversized count [1]
#define OFF_OVL (OFF_OVC + 1)            // oversized ids [G_N]
#define OFF_ENT (OFF_OVL + G_N)          // bucket entries [NBUCK*BCAP]
#define OFF_BOX (OFF_ENT + NBUCK * BCAP) // SWAR boxes uint4 [G_N]

__device__ __forceinline__ void quat_R(const float* quat, int g, float R[3][3]) {
    float q0 = quat[g * 4 + 0], q1 = quat[g * 4 + 1], q2 = quat[g * 4 + 2], q3 = quat[g * 4 + 3];
    float nrm = sqrtf(q0 * q0 + q1 * q1 + q2 * q2 + q3 * q3);
    float w = q0 / nrm, x = q1 / nrm, y = q2 / nrm, z = q3 / nrm;
    R[0][0] = 1.0f - 2.0f * (y * y + z * z);
    R[0][1] = 2.0f * (x * y - w * z);
    R[0][2] = 2.0f * (x * z + w * y);
    R[1][0] = 2.0f * (x * y + w * z);
    R[1][1] = 1.0f - 2.0f * (x * x + z * z);
    R[1][2] = 2.0f * (y * z - w * x);
    R[2][0] = 2.0f * (x * z - w * y);
    R[2][1] = 2.0f * (y * z + w * x);
    R[2][2] = 1.0f - 2.0f * (x * x + y * y);
}

__device__ __forceinline__ float radius_axis(const float R[3][3], float s2x, float s2y, float s2z, int a) {
    float dc = (R[a][0] * R[a][0]) * s2x + (R[a][1] * R[a][1]) * s2y + (R[a][2] * R[a][2]) * s2z;
    return sqrtf(7.8147279f) * sqrtf(dc);
}

__device__ __forceinline__ void grid_params(const float* ws, float gmn[3], float& vox) {
#pragma unroll
    for (int t = 0; t < 3; ++t) {
        float lo = ws[t], hi = ws[3 + t];
        float size = hi - lo;
        gmn[t] = lo - 0.1f * size;
    }
    vox = ws[6] * 3.0f;
}

// full score for gaussian g at point (px,py,pz) — exact R4/R5 expression chain
__device__ __forceinline__ float score_g(const float* __restrict__ pos, const float* __restrict__ scl,
                                         const float* __restrict__ quat, int g,
                                         float px, float py, float pz,
                                         float pp0, float pp1, float pp2,
                                         float pp4, float pp5, float pp8) {
    float R[3][3];
    quat_R(quat, g, R);
    float sx = scl[g * 3 + 0], sy = scl[g * 3 + 1], sz = scl[g * 3 + 2];
    float inv2x = 1.0f / (sx * sx), inv2y = 1.0f / (sy * sy), inv2z = 1.0f / (sz * sz);
    float C[3][3];
#pragma unroll
    for (int i = 0; i < 3; ++i) {
        float t0 = R[i][0] * inv2x, t1 = R[i][1] * inv2y, t2 = R[i][2] * inv2z;
#pragma unroll
        for (int k = 0; k < 3; ++k)
            C[i][k] = t0 * R[k][0] + t1 * R[k][1] + t2 * R[k][2];
    }
    float gx = pos[g * 3 + 0], gy = pos[g * 3 + 1], gz = pos[g * 3 + 2];
    float b0 = C[0][0] * gx + C[0][1] * gy + C[0][2] * gz;
    float b1 = C[1][0] * gx + C[1][1] * gy + C[1][2] * gz;
    float b2 = C[2][0] * gx + C[2][1] * gy + C[2][2] * gz;
    float c0 = b0 * gx + b1 * gy + b2 * gz;
    float log_norm = -2.7568155996140179f - (logf(sx) + logf(sy) + logf(sz));
    float s1 = pp0 * C[0][0];
    s1 = fmaf(pp1, C[0][1], s1);
    s1 = fmaf(pp2, C[0][2], s1);
    s1 = fmaf(pp1, C[1][0], s1);
    s1 = fmaf(pp4, C[1][1], s1);
    s1 = fmaf(pp5, C[1][2], s1);
    s1 = fmaf(pp2, C[2][0], s1);
    s1 = fmaf(pp5, C[2][1], s1);
    s1 = fmaf(pp8, C[2][2], s1);
    float d = px * b0;
    d = fmaf(py, b1, d);
    d = fmaf(pz, b2, d);
    float quad = fmaf(-2.0f, d, s1) + c0;
    return fmaf(-0.5f, quad, log_norm);
}

// float -> order-preserving u32 (ascending), and inverse
__device__ __forceinline__ unsigned f2ord(float f) {
    unsigned u = __float_as_uint(f);
    return (u & 0x80000000u) ? ~u : (u | 0x80000000u);
}
__device__ __forceinline__ float ord2f(unsigned u) {
    unsigned v = (u & 0x80000000u) ? (u ^ 0x80000000u) : ~u;
    return __uint_as_float(v);
}

// Stats via exact radix-select. Blocks 0-6: find the order statistics at ranks
// (r, r+1) and write the interpolated quantile. Digit selection is done by a
// single wave with a shuffle-scan (NO serial LDS walk — that was R6's 48 µs).
// Block 7 zeros the hash-table counters (ws is re-poisoned every launch).
__global__ __launch_bounds__(1024) void k_stats(const float* __restrict__ pos,
                                                const float* __restrict__ scl,
                                                const float* __restrict__ quat,
                                                float* __restrict__ ws) {
    int which = blockIdx.x;
    int tid = threadIdx.x;
    if (which == 7) {
        unsigned* u = (unsigned*)ws;
        for (int i = tid; i < NBUCK; i += 1024) u[OFF_CNT + i] = 0u;
        if (tid == 0) u[OFF_OVC] = 0u;
        return;
    }
    int a = (which < 3) ? which : (which < 6 ? which - 3 : 0);
    unsigned keys[2];
#pragma unroll
    for (int i = 0; i < 2; ++i) {
        int g = tid + i * 1024;
        float R[3][3];
        quat_R(quat, g, R);
        float sx = scl[g * 3 + 0], sy = scl[g * 3 + 1], sz = scl[g * 3 + 2];
        float rad = radius_axis(R, sx * sx, sy * sy, sz * sz, a);
        float v;
        if (which < 3)      v = pos[g * 3 + a] - rad;
        else if (which < 6) v = pos[g * 3 + a] + rad;
        else                v = rad;
        keys[i] = f2ord(v);
    }

    __shared__ unsigned hist[256];
    __shared__ unsigned sel[2];   // {digit, rank within digit group}
    __shared__ unsigned cntw[16]; // per-wave count of keys <= v_lo
    __shared__ unsigned minw[16]; // per-wave min of keys  > v_lo

    int rank0 = (which < 3) ? 20 : ((which < 6) ? 2026 : 1023);
    unsigned prefix = 0, pmask = 0, rank = (unsigned)rank0;
#pragma unroll
    for (int pass = 0; pass < 4; ++pass) {
        int shift = 24 - 8 * pass;
        if (tid < 256) hist[tid] = 0u;
        __syncthreads();
#pragma unroll
        for (int i = 0; i < 2; ++i) {
            unsigned k = keys[i];
            if ((k & pmask) == prefix) atomicAdd(&hist[(k >> shift) & 255u], 1u);
        }
        __syncthreads();
        if (tid < 64) {
            // lane owns bins [4t, 4t+3]; wave-scan group sums via shfl_up
            unsigned c0 = hist[tid * 4 + 0], c1 = hist[tid * 4 + 1];
            unsigned c2 = hist[tid * 4 + 2], c3 = hist[tid * 4 + 3];
            unsigned lsum = c0 + c1 + c2 + c3;
            unsigned v = lsum;
#pragma unroll
            for (int off = 1; off < 64; off <<= 1) {
                unsigned n = __shfl_up(v, off);
                if (tid >= off) v += n;
            }
            unsigned excl = v - lsum;   // exclusive prefix of this lane's group
            if (rank >= excl && rank < excl + lsum) {   // exactly one lane
                unsigned base = excl, d = tid * 4;
                if (rank >= base + c0) {
                    base += c0; ++d;
                    if (rank >= base + c1) {
                        base += c1; ++d;
                        if (rank >= base + c2) { base += c2; ++d; }
                    }
                }
                sel[0] = d;
                sel[1] = rank - base;
            }
        }
        __syncthreads();
        prefix |= sel[0] << shift;
        pmask |= 0xFFu << shift;
        rank = sel[1];
        // next pass's hist-clear + barrier orders sel reads vs next sel write
    }

    // prefix == ordered key at rank0 (exact). Find key at rank0+1:
    // vhi = prefix if duplicated at rank0+1, else min key > prefix.
    int wave = tid >> 6, lane = tid & 63;
    unsigned long long m0 = __ballot(keys[0] <= prefix);
    unsigned long long m1 = __ballot(keys[1] <= prefix);
    unsigned mn = 0xFFFFFFFFu;
    if (keys[0] > prefix) mn = keys[0];
    if (keys[1] > prefix && keys[1] < mn) mn = keys[1];
#pragma unroll
    for (int off = 32; off; off >>= 1) {
        unsigned o = __shfl_xor(mn, off);
        if (o < mn) mn = o;
    }
    if (lane == 0) {
        cntw[wave] = (unsigned)(__popcll(m0) + __popcll(m1));
        minw[wave] = mn;
    }
    __syncthreads();
    if (tid == 0) {
        unsigned total = 0, mall = 0xFFFFFFFFu;
#pragma unroll
        for (int w = 0; w < 16; ++w) {
            total += cntw[w];
            if (minw[w] < mall) mall = minw[w];
        }
        unsigned vlo = prefix;
        unsigned vhi = (total >= (unsigned)(rank0 + 2)) ? vlo : mall;
        float flo = ord2f(vlo), fhi = ord2f(vhi);
        float qq;
        if (which < 3) qq = 0.01f * 2047.0f;
        else if (which < 6) qq = 0.99f * 2047.0f;
        else qq = 0.5f * 2047.0f;
        int lo = (int)floorf(qq);
        float fr = qq - (float)lo;
        ws[which] = flo * (1.0f - fr) + fhi * fr;
    }
}

// Build: per-gaussian SWAR box + spatial-hash rasterization.
__global__ __launch_bounds__(256) void k_build(const float* __restrict__ pos,
                                               const float* __restrict__ scl,
                                               const float* __restrict__ quat,
                                               float* __restrict__ ws) {
    int g = blockIdx.x * blockDim.x + threadIdx.x;
    if (g >= G_N) return;
    float gmn[3], vox;
    grid_params(ws, gmn, vox);

    float R[3][3];
    quat_R(quat, g, R);
    float sx = scl[g * 3 + 0], sy = scl[g * 3 + 1], sz = scl[g * 3 + 2];
    float s2x = sx * sx, s2y = sy * sy, s2z = sz * sz;
    int gmini[3], gmaxi[3];
    long long nv = 1;
#pragma unroll
    for (int t = 0; t < 3; ++t) {
        float rad = radius_axis(R, s2x, s2y, s2z, t);
        float p = pos[g * 3 + t];
        int lo = (int)floorf(((p - rad) - gmn[t]) / vox);
        int hi = (int)floorf(((p + rad) - gmn[t]) / vox);
        lo = lo < 0 ? 0 : (lo > 1023 ? 1023 : lo);
        hi = hi < 0 ? 0 : (hi > 1023 ? 1023 : hi);
        gmini[t] = lo; gmaxi[t] = hi;
        nv *= (long long)(hi - lo + 1);
    }
    unsigned* u = (unsigned*)ws;
    bool oversized = nv > 64;
    if (oversized) {
        unsigned slot = atomicAdd(&u[OFF_OVC], 1u);
        u[OFF_OVL + slot] = (unsigned)g;
        gmini[0] = gmini[1] = gmini[2] = 0;
        gmaxi[0] = gmaxi[1] = gmaxi[2] = 2047;
    } else {
        for (int z = gmini[2]; z <= gmaxi[2]; ++z)
            for (int y = gmini[1]; y <= gmaxi[1]; ++y)
                for (int x = gmini[0]; x <= gmaxi[0]; ++x) {
                    unsigned h = ((unsigned)x * 73856093u ^ (unsigned)y * 19349663u
                                ^ (unsigned)z * 83492791u) & (NBUCK - 1);
                    unsigned old = atomicAdd(&u[OFF_CNT + h], 1u);
                    if (old < BCAP) u[OFF_ENT + h * BCAP + old] = (unsigned)g;
                }
    }
    unsigned long long A = (unsigned long long)gmini[0]
                         | ((unsigned long long)gmini[1] << 21)
                         | ((unsigned long long)gmini[2] << 42);
    unsigned long long B = ((unsigned long long)gmaxi[0]
                         | ((unsigned long long)gmaxi[1] << 21)
                         | ((unsigned long long)gmaxi[2] << 42)) | GUARD64;
    uint4* bx = (uint4*)(u + OFF_BOX);
    bx[g] = make_uint4((unsigned)(A & 0xffffffffu), (unsigned)(A >> 32),
                       (unsigned)(B & 0xffffffffu), (unsigned)(B >> 32));
}

// dedupe + strict-total-order (score desc, id asc) top-8 insert
__device__ __forceinline__ void ins8(float tv[K_TOP], int ti[K_TOP], float sc, int id) {
    bool dup = false;
#pragma unroll
    for (int j = 0; j < K_TOP; ++j) dup |= (ti[j] == id);
    if (dup) return;
    bool better = (sc > tv[K_TOP - 1]) || (sc == tv[K_TOP - 1] && id < ti[K_TOP - 1]);
    if (!better) return;
    tv[K_TOP - 1] = sc;
    ti[K_TOP - 1] = id;
#pragma unroll
    for (int j = K_TOP - 1; j > 0; --j) {
        bool sw = (tv[j] > tv[j - 1]) || (tv[j] == tv[j - 1] && ti[j] < ti[j - 1]);
        if (sw) {
            float fv = tv[j]; tv[j] = tv[j - 1]; tv[j - 1] = fv;
            int iv = ti[j]; ti[j] = ti[j - 1]; ti[j - 1] = iv;
        }
    }
}

// Match: one thread per point — bucket lookup + exact box verify + rare score.
__global__ __launch_bounds__(64) void k_match(const float* __restrict__ pos,
                                              const float* __restrict__ scl,
                                              const float* __restrict__ quat,
                                              const float* __restrict__ pts,
                                              const float* __restrict__ ws,
                                              float* __restrict__ out) {
    int p = blockIdx.x * 64 + threadIdx.x;
    float gmn[3], vox;
    grid_params(ws, gmn, vox);
    float px = pts[p * 3 + 0], py = pts[p * 3 + 1], pz = pts[p * 3 + 2];
    float fpx = floorf((px - gmn[0]) / vox);
    float fpy = floorf((py - gmn[1]) / vox);
    float fpz = floorf((pz - gmn[2]) / vox);
    bool valid = (fpx >= 0.0f) & (fpx <= 1023.0f) & (fpy >= 0.0f) & (fpy <= 1023.0f)
               & (fpz >= 0.0f) & (fpz <= 1023.0f);

    float pp0 = px * px, pp1 = px * py, pp2 = px * pz;
    float pp4 = py * py, pp5 = py * pz, pp8 = pz * pz;

    float tv[K_TOP];
    int ti[K_TOP];
#pragma unroll
    for (int j = 0; j < K_TOP; ++j) { tv[j] = -INFINITY; ti[j] = 0x7fffffff; }

    const unsigned* u = (const unsigned*)ws;
    const uint4* bx = (const uint4*)(u + OFF_BOX);

    if (valid) {
        int vx = (int)fpx, vy = (int)fpy, vz = (int)fpz;
        unsigned long long PV = (unsigned long long)(unsigned)vx
                              | ((unsigned long long)(unsigned)vy << 21)
                              | ((unsigned long long)(unsigned)vz << 42);
        unsigned long long PVG = PV | GUARD64;
        unsigned h = ((unsigned)vx * 73856093u ^ (unsigned)vy * 19349663u
                    ^ (unsigned)vz * 83492791u) & (NBUCK - 1);
        unsigned cnt = u[OFF_CNT + h];
        if (cnt <= BCAP) {
            for (unsigned i = 0; i < cnt; ++i) {
                int g = (int)u[OFF_ENT + h * BCAP + i];
                uint4 b4 = bx[g];
                unsigned long long A = (unsigned long long)b4.x | ((unsigned long long)b4.y << 32);
                unsigned long long B = (unsigned long long)b4.z | ((unsigned long long)b4.w << 32);
                if ((((PVG - A) & (B - PV)) & GUARD64) == GUARD64) {
                    float sc = score_g(pos, scl, quat, g, px, py, pz, pp0, pp1, pp2, pp4, pp5, pp8);
                    ins8(tv, ti, sc, g);
                }
            }
        } else {
            // bucket overflow: exact full scan (covers every gaussian incl. oversized)
            for (int g = 0; g < G_N; ++g) {
                uint4 b4 = bx[g];
                unsigned long long A = (unsigned long long)b4.x | ((unsigned long long)b4.y << 32);
                unsigned long long B = (unsigned long long)b4.z | ((unsigned long long)b4.w << 32);
                if ((((PVG - A) & (B - PV)) & GUARD64) == GUARD64) {
                    float sc = score_g(pos, scl, quat, g, px, py, pz, pp0, pp1, pp2, pp4, pp5, pp8);
                    ins8(tv, ti, sc, g);
                }
            }
        }
    }
    // oversized gaussians pass for every point (dedupe handles overlap with full scan)
    unsigned ovc = u[OFF_OVC];
    for (unsigned i = 0; i < ovc; ++i) {
        int g = (int)u[OFF_OVL + i];
        float sc = score_g(pos, scl, quat, g, px, py, pz, pp0, pp1, pp2, pp4, pp5, pp8);
        ins8(tv, ti, sc, g);
    }

#pragma unroll
    for (int j = 0; j < K_TOP; ++j) {
        bool fin = tv[j] > -INFINITY;
        out[p * K_TOP + j] = fin ? (float)ti[j] : -1.0f;
        out[P_N * K_TOP + p * K_TOP + j] = fin ? expf(tv[j]) : 0.0f;
    }
}

extern "C" void kernel_launch(void* const* d_in, const int* in_sizes, int n_in,
                              void* d_out, int out_size, void* d_ws, size_t ws_size,
                              hipStream_t stream) {
    const float* pos = (const float*)d_in[0];
    const float* scl = (const float*)d_in[1];
    const float* quat = (const float*)d_in[2];
    const float* pts = (const float*)d_in[3];
    float* ws = (float*)d_ws;
    float* out = (float*)d_out;

    k_stats<<<dim3(8), dim3(1024), 0, stream>>>(pos, scl, quat, ws);
    k_build<<<dim3(G_N / 256), dim3(256), 0, stream>>>(pos, scl, quat, ws);
    k_match<<<dim3(P_N / 64), dim3(64), 0, stream>>>(pos, scl, quat, pts, ws, out);
}